// Round 1
// baseline (782.793 us; speedup 1.0000x reference)
//
#include <hip/hip_runtime.h>
#include <math.h>

#define HH 256
#define WW 256
#define BB 8
#define NPIX (BB*HH*WW)      // 524288 elements per field
#define HWPLANE (HH*WW)      // 65536
#define EPSF 1e-12f

constexpr float L_T   = (float)(0.15*0.3);   // lambda*theta
constexpr float TAUT  = (float)(0.25/0.3);   // tau/theta
constexpr float THETA = 0.3f;

static __device__ __constant__ float GK[25] = {
  0.000874f, 0.006976f, 0.01386f,  0.006976f, 0.000874f,
  0.006976f, 0.0557f,   0.110656f, 0.0557f,   0.006976f,
  0.01386f,  0.110656f, 0.219833f, 0.110656f, 0.01386f,
  0.006976f, 0.0557f,   0.110656f, 0.0557f,   0.006976f,
  0.000874f, 0.006976f, 0.01386f,  0.006976f, 0.000874f };

// ---- K1: grayscale both images + global min/max (uint-ordered atomics, vals >= 0)
__global__ void k_gray_minmax(const float* __restrict__ x1, const float* __restrict__ x2,
                              float* __restrict__ g1, float* __restrict__ g2,
                              unsigned int* __restrict__ mnmx) {
    int idx = blockIdx.x*blockDim.x + threadIdx.x;   // [0, 2*NPIX)
    int img = idx >> 19;
    int rem = idx & (NPIX-1);
    const float* x = img ? x2 : x1;
    float* g = img ? g2 : g1;
    int b = rem >> 16;
    int pix = rem & (HWPLANE-1);
    const float* px = x + (size_t)b*3*HWPLANE + pix;
    float gray = 0.114f*px[0] + 0.587f*px[HWPLANE] + 0.299f*px[2*HWPLANE];
    g[rem] = gray;
    float mn = gray, mx = gray;
    #pragma unroll
    for (int off = 32; off; off >>= 1) {
        mn = fminf(mn, __shfl_down(mn, off, 64));
        mx = fmaxf(mx, __shfl_down(mx, off, 64));
    }
    if ((threadIdx.x & 63) == 0) {
        atomicMin(&mnmx[0], __float_as_uint(mn));
        atomicMax(&mnmx[1], __float_as_uint(mx));
    }
}

// ---- K2: normalize (fused) + 5x5 Gaussian, zero 'SAME' padding of the normalized image
__global__ void k_smooth(const float* __restrict__ g1, const float* __restrict__ g2,
                         float* __restrict__ s1, float* __restrict__ s2,
                         const unsigned int* __restrict__ mnmx) {
    int idx = blockIdx.x*blockDim.x + threadIdx.x;   // [0, 2*NPIX)
    int img = idx >> 19;
    int rem = idx & (NPIX-1);
    const float* g = img ? g2 : g1;
    float* s = img ? s2 : s1;
    float mn = __uint_as_float(mnmx[0]);
    float mx = __uint_as_float(mnmx[1]);
    float inv = 255.0f / (mx - mn);
    int y = (rem >> 8) & 255, x = rem & 255;
    const float* gb = g + (rem & ~(HWPLANE-1));      // batch-plane base
    float acc = 0.f;
    #pragma unroll
    for (int i = 0; i < 5; ++i) {
        int yy = y + i - 2;
        if (yy < 0 || yy >= HH) continue;
        #pragma unroll
        for (int j = 0; j < 5; ++j) {
            int xx = x + j - 2;
            if (xx < 0 || xx >= WW) continue;
            float v = (gb[yy*WW + xx] - mn) * inv;
            acc += v * GK[i*5 + j];
        }
    }
    s[rem] = acc;
}

// ---- K3: centered grad of s2 (one-sided*0.5 at borders) + rho_c = s2 - s1.
// NOTE: rho_c may alias s1 (own-pixel read->write only) — no __restrict__ on those.
__global__ void k_grad_rhoc(const float* s1, const float* __restrict__ s2,
                            float* __restrict__ dxw, float* __restrict__ dyw,
                            float* rho_c) {
    int idx = blockIdx.x*blockDim.x + threadIdx.x;   // [0, NPIX)
    int y = (idx >> 8) & 255, x = idx & 255;
    float xp = s2[(x < WW-1) ? idx+1  : idx];
    float xm = s2[(x > 0)    ? idx-1  : idx];
    float yp = s2[(y < HH-1) ? idx+WW : idx];
    float ym = s2[(y > 0)    ? idx-WW : idx];
    float r  = s2[idx] - s1[idx];
    dxw[idx]   = 0.5f*(xp - xm);
    dyw[idx]   = 0.5f*(yp - ym);
    rho_c[idx] = r;
}

// ---- K4: thresholding step + u update (u in-place; p read at -1 halo only)
__global__ void k_update_u(const float* __restrict__ rho_c, const float* __restrict__ dxw,
                           const float* __restrict__ dyw,
                           float* __restrict__ u1, float* __restrict__ u2,
                           const float* __restrict__ p11, const float* __restrict__ p12,
                           const float* __restrict__ p21, const float* __restrict__ p22,
                           float* __restrict__ out, int last) {
    int idx = blockIdx.x*blockDim.x + threadIdx.x;   // [0, NPIX)
    int b = idx >> 16, y = (idx >> 8) & 255, x = idx & 255;
    float dxv = dxw[idx], dyv = dyw[idx];
    float u1v = u1[idx],  u2v = u2[idx];
    float rho  = rho_c[idx] + dxv*u1v + dyv*u2v + EPSF;
    float grad = dxv*dxv + dyv*dyv + EPSF;
    float th = L_T * grad;
    float coef;
    if (rho < -th)        coef =  L_T;
    else if (rho > th)    coef = -L_T;
    else if (grad > EPSF) coef = -rho / grad;
    else                  coef = 0.0f;
    float v1 = coef*dxv + u1v;
    float v2 = coef*dyv + u2v;
    float p11c = p11[idx], p12c = p12[idx], p21c = p21[idx], p22c = p22[idx];
    float d1 = ((x==0) ? p11c : (x==WW-1) ? -p11[idx-1]  : p11c - p11[idx-1])
             + ((y==0) ? p12c : (y==HH-1) ? -p12[idx-WW] : p12c - p12[idx-WW]);
    float d2 = ((x==0) ? p21c : (x==WW-1) ? -p21[idx-1]  : p21c - p21[idx-1])
             + ((y==0) ? p22c : (y==HH-1) ? -p22[idx-WW] : p22c - p22[idx-WW]);
    float u1n = v1 + THETA*d1;
    float u2n = v2 + THETA*d2;
    if (last) {
        float* o = out + (size_t)b*3*HWPLANE + (idx & (HWPLANE-1));
        o[0]          = u1n;
        o[HWPLANE]    = u2n;
        o[2*HWPLANE]  = rho;
    } else {
        u1[idx] = u1n;
        u2[idx] = u2n;
    }
}

// ---- K5: dual variable update (p in-place; u read at +1 halo only)
__global__ void k_update_p(const float* __restrict__ u1, const float* __restrict__ u2,
                           float* __restrict__ p11, float* __restrict__ p12,
                           float* __restrict__ p21, float* __restrict__ p22) {
    int idx = blockIdx.x*blockDim.x + threadIdx.x;   // [0, NPIX)
    int y = (idx >> 8) & 255, x = idx & 255;
    float u1c = u1[idx], u2c = u2[idx];
    float u1x = (x < WW-1) ? u1[idx+1]  - u1c : 0.f;
    float u1y = (y < HH-1) ? u1[idx+WW] - u1c : 0.f;
    float u2x = (x < WW-1) ? u2[idx+1]  - u2c : 0.f;
    float u2y = (y < HH-1) ? u2[idx+WW] - u2c : 0.f;
    float ng1 = 1.0f + TAUT*sqrtf(u1x*u1x + u1y*u1y + EPSF);
    float ng2 = 1.0f + TAUT*sqrtf(u2x*u2x + u2y*u2y + EPSF);
    p11[idx] = (p11[idx] + TAUT*u1x) / ng1;
    p12[idx] = (p12[idx] + TAUT*u1y) / ng1;
    p21[idx] = (p21[idx] + TAUT*u2x) / ng2;
    p22[idx] = (p22[idx] + TAUT*u2y) / ng2;
}

extern "C" void kernel_launch(void* const* d_in, const int* in_sizes, int n_in,
                              void* d_out, int out_size, void* d_ws, size_t ws_size,
                              hipStream_t stream) {
    const float* x1 = (const float*)d_in[0];
    const float* x2 = (const float*)d_in[1];
    float* out = (float*)d_out;

    char* ws = (char*)d_ws;
    unsigned int* mnmx = (unsigned int*)ws;
    float* F = (float*)(ws + 256);
    const size_t FB = (size_t)NPIX * sizeof(float);   // 2 MiB per field
    float* g1  = F + 0*(size_t)NPIX;   // later: dxw
    float* g2  = F + 1*(size_t)NPIX;   // later: dyw
    float* s1  = F + 2*(size_t)NPIX;   // later: rho_c (in-place)
    float* s2  = F + 3*(size_t)NPIX;
    float* p11 = F + 4*(size_t)NPIX;
    float* p12 = F + 5*(size_t)NPIX;
    float* p21 = F + 6*(size_t)NPIX;
    float* p22 = F + 7*(size_t)NPIX;
    float* u1  = F + 8*(size_t)NPIX;
    float* u2  = F + 9*(size_t)NPIX;
    float* dxw = g1;
    float* dyw = g2;
    float* rhoc = s1;

    // init: min := huge (0x7F7F7F7F), max := 0 (gray >= 0); p,u := 0 (contiguous 6 fields)
    hipMemsetAsync(mnmx,     0x7F, 4, stream);
    hipMemsetAsync(mnmx + 1, 0x00, 4, stream);
    hipMemsetAsync(p11, 0, 6*FB, stream);

    k_gray_minmax<<<dim3(4096), dim3(256), 0, stream>>>(x1, x2, g1, g2, mnmx);
    k_smooth     <<<dim3(4096), dim3(256), 0, stream>>>(g1, g2, s1, s2, mnmx);
    k_grad_rhoc  <<<dim3(2048), dim3(256), 0, stream>>>(s1, s2, dxw, dyw, rhoc);

    for (int it = 0; it < 30; ++it) {
        k_update_u<<<dim3(2048), dim3(256), 0, stream>>>(rhoc, dxw, dyw, u1, u2,
                                                         p11, p12, p21, p22, out, it == 29);
        if (it < 29)
            k_update_p<<<dim3(2048), dim3(256), 0, stream>>>(u1, u2, p11, p12, p21, p22);
    }
}

// Round 2
// 419.774 us; speedup vs baseline: 1.8648x; 1.8648x over previous
//
#include <hip/hip_runtime.h>
#include <math.h>

#define HH 256
#define WW 256
#define BB 8
#define NPIX (BB*HH*WW)      // 524288 elements per field
#define HWPLANE (HH*WW)      // 65536
#define EPSF 1e-12f

constexpr float L_T   = (float)(0.15*0.3);   // lambda*theta
constexpr float TAUT  = (float)(0.25/0.3);   // tau/theta
constexpr float THETA = 0.3f;

static __device__ __constant__ float GK[25] = {
  0.000874f, 0.006976f, 0.01386f,  0.006976f, 0.000874f,
  0.006976f, 0.0557f,   0.110656f, 0.0557f,   0.006976f,
  0.01386f,  0.110656f, 0.219833f, 0.110656f, 0.01386f,
  0.006976f, 0.0557f,   0.110656f, 0.0557f,   0.006976f,
  0.000874f, 0.006976f, 0.01386f,  0.006976f, 0.000874f };

// ---- K1: grayscale both images + global min/max.
// Grid-stride, 256 blocks: per-thread accum -> wave shuffle reduce -> LDS block
// reduce -> ONE atomic pair per block (512 total; R1 had 32768 serialized
// same-address atomics = 374us).
__global__ void k_gray_minmax(const float* __restrict__ x1, const float* __restrict__ x2,
                              float* __restrict__ g1, float* __restrict__ g2,
                              unsigned int* __restrict__ mnmx) {
    __shared__ float smn[4], smx[4];
    float mn = 1e30f, mx = -1e30f;
    int stride = gridDim.x * blockDim.x;
    for (int idx = blockIdx.x*blockDim.x + threadIdx.x; idx < 2*NPIX; idx += stride) {
        int img = idx >> 19;
        int rem = idx & (NPIX-1);
        const float* x = img ? x2 : x1;
        float* g = img ? g2 : g1;
        int b = rem >> 16;
        int pix = rem & (HWPLANE-1);
        const float* px = x + (size_t)b*3*HWPLANE + pix;
        float gray = 0.114f*px[0] + 0.587f*px[HWPLANE] + 0.299f*px[2*HWPLANE];
        g[rem] = gray;
        mn = fminf(mn, gray);
        mx = fmaxf(mx, gray);
    }
    #pragma unroll
    for (int off = 32; off; off >>= 1) {
        mn = fminf(mn, __shfl_down(mn, off, 64));
        mx = fmaxf(mx, __shfl_down(mx, off, 64));
    }
    int wid = threadIdx.x >> 6;
    if ((threadIdx.x & 63) == 0) { smn[wid] = mn; smx[wid] = mx; }
    __syncthreads();
    if (threadIdx.x == 0) {
        mn = fminf(fminf(smn[0], smn[1]), fminf(smn[2], smn[3]));
        mx = fmaxf(fmaxf(smx[0], smx[1]), fmaxf(smx[2], smx[3]));
        atomicMin(&mnmx[0], __float_as_uint(mn));   // gray >= 0: uint order == float order
        atomicMax(&mnmx[1], __float_as_uint(mx));
    }
}

// ---- K2: normalize (fused) + 5x5 Gaussian, zero 'SAME' padding of the normalized image
__global__ void k_smooth(const float* __restrict__ g1, const float* __restrict__ g2,
                         float* __restrict__ s1, float* __restrict__ s2,
                         const unsigned int* __restrict__ mnmx) {
    int idx = blockIdx.x*blockDim.x + threadIdx.x;   // [0, 2*NPIX)
    int img = idx >> 19;
    int rem = idx & (NPIX-1);
    const float* g = img ? g2 : g1;
    float* s = img ? s2 : s1;
    float mn = __uint_as_float(mnmx[0]);
    float mx = __uint_as_float(mnmx[1]);
    float inv = 255.0f / (mx - mn);
    int y = (rem >> 8) & 255, x = rem & 255;
    const float* gb = g + (rem & ~(HWPLANE-1));      // batch-plane base
    float acc = 0.f;
    #pragma unroll
    for (int i = 0; i < 5; ++i) {
        int yy = y + i - 2;
        if (yy < 0 || yy >= HH) continue;
        #pragma unroll
        for (int j = 0; j < 5; ++j) {
            int xx = x + j - 2;
            if (xx < 0 || xx >= WW) continue;
            float v = (gb[yy*WW + xx] - mn) * inv;
            acc += v * GK[i*5 + j];
        }
    }
    s[rem] = acc;
}

// ---- K3: centered grad of s2 (one-sided*0.5 at borders) + rho_c = s2 - s1.
// NOTE: rho_c may alias s1 (own-pixel read->write only) — no __restrict__ on those.
__global__ void k_grad_rhoc(const float* s1, const float* __restrict__ s2,
                            float* __restrict__ dxw, float* __restrict__ dyw,
                            float* rho_c) {
    int idx = blockIdx.x*blockDim.x + threadIdx.x;   // [0, NPIX)
    int y = (idx >> 8) & 255, x = idx & 255;
    float xp = s2[(x < WW-1) ? idx+1  : idx];
    float xm = s2[(x > 0)    ? idx-1  : idx];
    float yp = s2[(y < HH-1) ? idx+WW : idx];
    float ym = s2[(y > 0)    ? idx-WW : idx];
    float r  = s2[idx] - s1[idx];
    dxw[idx]   = 0.5f*(xp - xm);
    dyw[idx]   = 0.5f*(yp - ym);
    rho_c[idx] = r;
}

// ---- K4: thresholding step + u update (u in-place; p read at -1 halo only)
__global__ void k_update_u(const float* __restrict__ rho_c, const float* __restrict__ dxw,
                           const float* __restrict__ dyw,
                           float* __restrict__ u1, float* __restrict__ u2,
                           const float* __restrict__ p11, const float* __restrict__ p12,
                           const float* __restrict__ p21, const float* __restrict__ p22,
                           float* __restrict__ out, int last) {
    int idx = blockIdx.x*blockDim.x + threadIdx.x;   // [0, NPIX)
    int b = idx >> 16, y = (idx >> 8) & 255, x = idx & 255;
    float dxv = dxw[idx], dyv = dyw[idx];
    float u1v = u1[idx],  u2v = u2[idx];
    float rho  = rho_c[idx] + dxv*u1v + dyv*u2v + EPSF;
    float grad = dxv*dxv + dyv*dyv + EPSF;
    float th = L_T * grad;
    float coef;
    if (rho < -th)        coef =  L_T;
    else if (rho > th)    coef = -L_T;
    else if (grad > EPSF) coef = -rho / grad;
    else                  coef = 0.0f;
    float v1 = coef*dxv + u1v;
    float v2 = coef*dyv + u2v;
    float p11c = p11[idx], p12c = p12[idx], p21c = p21[idx], p22c = p22[idx];
    float d1 = ((x==0) ? p11c : (x==WW-1) ? -p11[idx-1]  : p11c - p11[idx-1])
             + ((y==0) ? p12c : (y==HH-1) ? -p12[idx-WW] : p12c - p12[idx-WW]);
    float d2 = ((x==0) ? p21c : (x==WW-1) ? -p21[idx-1]  : p21c - p21[idx-1])
             + ((y==0) ? p22c : (y==HH-1) ? -p22[idx-WW] : p22c - p22[idx-WW]);
    float u1n = v1 + THETA*d1;
    float u2n = v2 + THETA*d2;
    if (last) {
        float* o = out + (size_t)b*3*HWPLANE + (idx & (HWPLANE-1));
        o[0]          = u1n;
        o[HWPLANE]    = u2n;
        o[2*HWPLANE]  = rho;
    } else {
        u1[idx] = u1n;
        u2[idx] = u2n;
    }
}

// ---- K5: dual variable update (p in-place; u read at +1 halo only)
__global__ void k_update_p(const float* __restrict__ u1, const float* __restrict__ u2,
                           float* __restrict__ p11, float* __restrict__ p12,
                           float* __restrict__ p21, float* __restrict__ p22) {
    int idx = blockIdx.x*blockDim.x + threadIdx.x;   // [0, NPIX)
    int y = (idx >> 8) & 255, x = idx & 255;
    float u1c = u1[idx], u2c = u2[idx];
    float u1x = (x < WW-1) ? u1[idx+1]  - u1c : 0.f;
    float u1y = (y < HH-1) ? u1[idx+WW] - u1c : 0.f;
    float u2x = (x < WW-1) ? u2[idx+1]  - u2c : 0.f;
    float u2y = (y < HH-1) ? u2[idx+WW] - u2c : 0.f;
    float ng1 = 1.0f + TAUT*sqrtf(u1x*u1x + u1y*u1y + EPSF);
    float ng2 = 1.0f + TAUT*sqrtf(u2x*u2x + u2y*u2y + EPSF);
    p11[idx] = (p11[idx] + TAUT*u1x) / ng1;
    p12[idx] = (p12[idx] + TAUT*u1y) / ng1;
    p21[idx] = (p21[idx] + TAUT*u2x) / ng2;
    p22[idx] = (p22[idx] + TAUT*u2y) / ng2;
}

extern "C" void kernel_launch(void* const* d_in, const int* in_sizes, int n_in,
                              void* d_out, int out_size, void* d_ws, size_t ws_size,
                              hipStream_t stream) {
    const float* x1 = (const float*)d_in[0];
    const float* x2 = (const float*)d_in[1];
    float* out = (float*)d_out;

    char* ws = (char*)d_ws;
    unsigned int* mnmx = (unsigned int*)ws;
    float* F = (float*)(ws + 256);
    const size_t FB = (size_t)NPIX * sizeof(float);   // 2 MiB per field
    float* g1  = F + 0*(size_t)NPIX;   // later: dxw
    float* g2  = F + 1*(size_t)NPIX;   // later: dyw
    float* s1  = F + 2*(size_t)NPIX;   // later: rho_c (in-place)
    float* s2  = F + 3*(size_t)NPIX;
    float* p11 = F + 4*(size_t)NPIX;
    float* p12 = F + 5*(size_t)NPIX;
    float* p21 = F + 6*(size_t)NPIX;
    float* p22 = F + 7*(size_t)NPIX;
    float* u1  = F + 8*(size_t)NPIX;
    float* u2  = F + 9*(size_t)NPIX;
    float* dxw = g1;
    float* dyw = g2;
    float* rhoc = s1;

    // init: min := huge (0x7F7F7F7F), max := 0 (gray >= 0); p,u := 0 (contiguous 6 fields)
    hipMemsetAsync(mnmx,     0x7F, 4, stream);
    hipMemsetAsync(mnmx + 1, 0x00, 4, stream);
    hipMemsetAsync(p11, 0, 6*FB, stream);

    k_gray_minmax<<<dim3(256),  dim3(256), 0, stream>>>(x1, x2, g1, g2, mnmx);
    k_smooth     <<<dim3(4096), dim3(256), 0, stream>>>(g1, g2, s1, s2, mnmx);
    k_grad_rhoc  <<<dim3(2048), dim3(256), 0, stream>>>(s1, s2, dxw, dyw, rhoc);

    for (int it = 0; it < 30; ++it) {
        k_update_u<<<dim3(2048), dim3(256), 0, stream>>>(rhoc, dxw, dyw, u1, u2,
                                                         p11, p12, p21, p22, out, it == 29);
        if (it < 29)
            k_update_p<<<dim3(2048), dim3(256), 0, stream>>>(u1, u2, p11, p12, p21, p22);
    }
}